// Round 8
// baseline (805.564 us; speedup 1.0000x reference)
//
#include <hip/hip_runtime.h>
#include <math.h>

#define NNODE 200000
#define NEDGE 1000000
#define HEDGE 500000

typedef __attribute__((ext_vector_type(8))) short bf16x8;
typedef __attribute__((ext_vector_type(4))) float f32x4;

// ---- float <-> bf16 (RNE) ----
__device__ __forceinline__ unsigned short f2bf(float f) {
  unsigned u = __float_as_uint(f);
  unsigned r = (u + 0x7fffu + ((u >> 16) & 1u)) >> 16;
  return (unsigned short)r;
}
__device__ __forceinline__ float bf2f(unsigned short h) {
  return __uint_as_float(((unsigned)h) << 16);
}

// ======================= CSR build =======================
__global__ void k_deg(const int* __restrict__ ei, const int* __restrict__ c2li,
                      int* __restrict__ degA, int* __restrict__ degB) {
  int j = blockIdx.x * 256 + threadIdx.x;
  if (j < NEDGE) atomicAdd(&degA[ei[2 * j + 1]], 1);
  if (j < HEDGE) {
    int jj = c2li[j];
    atomicAdd(&degB[ei[2 * jj]], 1);
  }
}

// Wave-aggregated CSR range allocator (bucket order irrelevant for gathers).
__global__ void k_alloc(const int* __restrict__ degA, int* __restrict__ offA, int* __restrict__ curA,
                        const int* __restrict__ degB, int* __restrict__ offB, int* __restrict__ curB,
                        int* __restrict__ cursors) {
  int i = blockIdx.x * 256 + threadIdx.x;
  int lane = threadIdx.x & 63;
  bool act = i < NNODE;
#pragma unroll
  for (int which = 0; which < 2; ++which) {
    const int* deg = which ? degB : degA;
    int* off = which ? offB : offA;
    int* cur = which ? curB : curA;
    int d = act ? deg[i] : 0;
    int incl = d;
#pragma unroll
    for (int s = 1; s < 64; s <<= 1) {
      int v = __shfl_up(incl, s, 64);
      if (lane >= s) incl += v;
    }
    int base = 0;
    if (lane == 63) base = atomicAdd(&cursors[which], incl);
    base = __shfl(base, 63, 64);
    if (act) {
      int o = base + incl - d;
      off[i] = o;
      cur[i] = o;
    }
  }
}

__global__ void k_fill(const int* __restrict__ ei, const int* __restrict__ c2li,
                       int* __restrict__ curA, int* __restrict__ listA,
                       int* __restrict__ curB, int* __restrict__ listB) {
  int j = blockIdx.x * 256 + threadIdx.x;
  if (j < NEDGE) {
    int d = ei[2 * j + 1];
    int s = atomicAdd(&curA[d], 1);
    listA[s] = j;
  }
  if (j < HEDGE) {
    int jj = c2li[j];
    int sn = ei[2 * jj], dn = ei[2 * jj + 1];
    int s = atomicAdd(&curB[sn], 1);
    listB[s] = dn;
  }
}

// ---- guarded online-LSE pair merge (handles empty partials m=-inf) ----
__device__ __forceinline__ void lse_merge1(float& m, float& s, float mo, float so) {
  float nm = fmaxf(m, mo);
  if (nm == -INFINITY) return;  // both empty
  float ea = (m == -INFINITY) ? 0.f : __expf(m - nm);
  float eb = (mo == -INFINITY) ? 0.f : __expf(mo - nm);
  s = s * ea + so * eb;
  m = nm;
}

// ---- fused gather: aggr (task A) + lse (task B), one wave per node ----
// 4x16-lane groups x 4 unroll slots = 16 independent list->row load chains
// per wave (deg<=16 nodes finish in ONE memory round-trip). Slot merge is
// register-local; cross-group combine via shfl_xor(16|32) butterfly.
__global__ void k_gather(const int* __restrict__ offA, const int* __restrict__ degA,
                         const int* __restrict__ listA,
                         const int* __restrict__ offB, const int* __restrict__ degB,
                         const int* __restrict__ listB,
                         const float* __restrict__ emb,
                         float* __restrict__ aggr, float* __restrict__ lse, int gN) {
  int lane = threadIdx.x & 63, wv = threadIdx.x >> 6;
  int g = lane >> 4, l16 = lane & 15;
  bool taskA = blockIdx.x < gN;
  int node = (taskA ? blockIdx.x : blockIdx.x - gN) * 4 + wv;
  if (node >= NNODE) return;
  if (taskA) {
    int o = offA[node], n = degA[node];
    float4 s[4];
#pragma unroll
    for (int u = 0; u < 4; ++u) s[u] = (float4){0.f, 0.f, 0.f, 0.f};
    for (int i0 = 0; i0 < n; i0 += 16) {
      int idx[4];
      bool on[4];
#pragma unroll
      for (int u = 0; u < 4; ++u) {
        int i = i0 + 4 * u + g;
        on[u] = i < n;
        idx[u] = on[u] ? listA[o + i] : 0;
      }
#pragma unroll
      for (int u = 0; u < 4; ++u) {
        if (on[u]) {
          float4 v = *(const float4*)(emb + (size_t)idx[u] * 64 + 4 * l16);
          s[u].x += v.x; s[u].y += v.y; s[u].z += v.z; s[u].w += v.w;
        }
      }
    }
    float sx = s[0].x + s[1].x + s[2].x + s[3].x;
    float sy = s[0].y + s[1].y + s[2].y + s[3].y;
    float sz = s[0].z + s[1].z + s[2].z + s[3].z;
    float sw = s[0].w + s[1].w + s[2].w + s[3].w;
#pragma unroll
    for (int mask = 16; mask <= 32; mask <<= 1) {
      sx += __shfl_xor(sx, mask, 64);
      sy += __shfl_xor(sy, mask, 64);
      sz += __shfl_xor(sz, mask, 64);
      sw += __shfl_xor(sw, mask, 64);
    }
    if (g == 0) {
      float4 v = {sx, sy, sz, sw};
      *(float4*)(aggr + (size_t)node * 64 + 4 * l16) = v;  // empty nodes -> 0
    }
  } else {
    int o = offB[node], n = degB[node];
    if (n == 0) return;  // lse only read at nodes with c2l out-edges
    float4 m[4], s[4];
#pragma unroll
    for (int u = 0; u < 4; ++u) {
      m[u] = (float4){-INFINITY, -INFINITY, -INFINITY, -INFINITY};
      s[u] = (float4){0.f, 0.f, 0.f, 0.f};
    }
    for (int i0 = 0; i0 < n; i0 += 16) {
      int idx[4];
      bool on[4];
#pragma unroll
      for (int u = 0; u < 4; ++u) {
        int i = i0 + 4 * u + g;
        on[u] = i < n;
        idx[u] = on[u] ? listB[o + i] : 0;
      }
#pragma unroll
      for (int u = 0; u < 4; ++u) {
        if (on[u]) {
          float4 v = *(const float4*)(emb + (size_t)idx[u] * 64 + 4 * l16);
          float nm;
          nm = fmaxf(m[u].x, v.x); s[u].x = s[u].x * __expf(m[u].x - nm) + __expf(v.x - nm); m[u].x = nm;
          nm = fmaxf(m[u].y, v.y); s[u].y = s[u].y * __expf(m[u].y - nm) + __expf(v.y - nm); m[u].y = nm;
          nm = fmaxf(m[u].z, v.z); s[u].z = s[u].z * __expf(m[u].z - nm) + __expf(v.z - nm); m[u].z = nm;
          nm = fmaxf(m[u].w, v.w); s[u].w = s[u].w * __expf(m[u].w - nm) + __expf(v.w - nm); m[u].w = nm;
        }
      }
    }
    float mx = m[0].x, my = m[0].y, mz = m[0].z, mw = m[0].w;
    float sx = s[0].x, sy = s[0].y, sz = s[0].z, sw = s[0].w;
#pragma unroll
    for (int u = 1; u < 4; ++u) {
      lse_merge1(mx, sx, m[u].x, s[u].x);
      lse_merge1(my, sy, m[u].y, s[u].y);
      lse_merge1(mz, sz, m[u].z, s[u].z);
      lse_merge1(mw, sw, m[u].w, s[u].w);
    }
#pragma unroll
    for (int mask = 16; mask <= 32; mask <<= 1) {
      lse_merge1(mx, sx, __shfl_xor(mx, mask, 64), __shfl_xor(sx, mask, 64));
      lse_merge1(my, sy, __shfl_xor(my, mask, 64), __shfl_xor(sy, mask, 64));
      lse_merge1(mz, sz, __shfl_xor(mz, mask, 64), __shfl_xor(sz, mask, 64));
      lse_merge1(mw, sw, __shfl_xor(mw, mask, 64), __shfl_xor(sw, mask, 64));
    }
    if (g == 0) {
      float4 v = {__logf(sx) + mx, __logf(sy) + my, __logf(sz) + mz, __logf(sw) + mw};
      *(float4*)(lse + (size_t)node * 64 + 4 * l16) = v;
    }
  }
}

// ======================= weight prep =======================
// Frag-ordered bf16 hi/lo. value = W[32s + 8*(lane>>4) + j][16c + (lane&15)].
// Elem offsets: l2c L1/L2/L3: 0/4096/8192; merge_W0: 12288 (K=128);
// merge_W L1/L2: 20480/24576; c2l L1/L2/L3: 28672/32768/36864. Total 40960.
__global__ void k_prepw(const float* __restrict__ l2cW, const float* __restrict__ mW0,
                        const float* __restrict__ mW, const float* __restrict__ c2lW,
                        unsigned short* __restrict__ WH, unsigned short* __restrict__ WL) {
  int tid = blockIdx.x * 256 + threadIdx.x;
  if (tid >= 40960) return;
  const float* src;
  int base;
  if (tid < 12288) {
    int m = tid / 4096; src = l2cW + m * 4096; base = m * 4096;
  } else if (tid < 20480) {
    src = mW0; base = 12288;
  } else if (tid < 28672) {
    int m = (tid - 20480) / 4096; src = mW + m * 4096; base = 20480 + m * 4096;
  } else {
    int m = (tid - 28672) / 4096; src = c2lW + m * 4096; base = 28672 + m * 4096;
  }
  int local = tid - base;
  int f = local >> 9;           // frag id = s*4+c
  int l = (local >> 3) & 63;    // lane
  int j = local & 7;            // elem
  int s = f >> 2, c = f & 3;
  int k = 32 * s + 8 * (l >> 4) + j;
  int col = 16 * c + (l & 15);
  float v = src[k * 64 + col];
  unsigned short hh = f2bf(v);
  WH[tid] = hh;
  WL[tid] = f2bf(v - bf2f(hh));
}

// ======================= MFMA MLP machinery =======================
// Wave-private LDS tile xs[16 rows][64 cols] f32, XOR-swizzled:
//   dword(row,col) = row*64 + (((col>>2) ^ row) & 15)*4 + (col & 3)

__device__ __forceinline__ void split8(float t0, float t1, float t2, float t3,
                                       float t4, float t5, float t6, float t7,
                                       bf16x8& ah, bf16x8& al) {
  unsigned short h;
  h = f2bf(t0); ah[0] = (short)h; al[0] = (short)f2bf(t0 - bf2f(h));
  h = f2bf(t1); ah[1] = (short)h; al[1] = (short)f2bf(t1 - bf2f(h));
  h = f2bf(t2); ah[2] = (short)h; al[2] = (short)f2bf(t2 - bf2f(h));
  h = f2bf(t3); ah[3] = (short)h; al[3] = (short)f2bf(t3 - bf2f(h));
  h = f2bf(t4); ah[4] = (short)h; al[4] = (short)f2bf(t4 - bf2f(h));
  h = f2bf(t5); ah[5] = (short)h; al[5] = (short)f2bf(t5 - bf2f(h));
  h = f2bf(t6); ah[6] = (short)h; al[6] = (short)f2bf(t6 - bf2f(h));
  h = f2bf(t7); ah[7] = (short)h; al[7] = (short)f2bf(t7 - bf2f(h));
}

// Split-bf16: acc += al*wh + ah*wl + ah*wh (misses only lo*lo ~ 2^-18).
template <int NS, bool RELU, bool FLIP>
__device__ __forceinline__ void mfma_layer(const float* xw, int lane,
                                           const unsigned short* __restrict__ wh_,
                                           const unsigned short* __restrict__ wl_,
                                           const float* __restrict__ bias, f32x4 (&acc)[4]) {
  int col15 = lane & 15, hq = lane >> 4;
#pragma unroll
  for (int c = 0; c < 4; ++c) {
    float bv = bias[16 * c + col15];
    acc[c] = (f32x4){bv, bv, bv, bv};
  }
#pragma unroll
  for (int s = 0; s < NS; ++s) {
    int flip = (FLIP && s >= NS / 2);
    int arow = flip ? (col15 ^ 1) : col15;
    int ks = flip ? (s - NS / 2) : s;
    const float* xr = xw + arow * 64;
    float4 A0 = *(const float4*)(xr + ((((8 * ks + 2 * hq + 0) ^ arow) & 15) << 2));
    float4 A1 = *(const float4*)(xr + ((((8 * ks + 2 * hq + 1) ^ arow) & 15) << 2));
    bf16x8 ah, al;
    split8(A0.x, A0.y, A0.z, A0.w, A1.x, A1.y, A1.z, A1.w, ah, al);
#pragma unroll
    for (int c = 0; c < 4; ++c) {
      const unsigned short* wo = wh_ + ((size_t)((s * 4 + c) * 64 + lane) * 8);
      const unsigned short* lo = wl_ + ((size_t)((s * 4 + c) * 64 + lane) * 8);
      bf16x8 wh = *(const bf16x8*)wo;
      bf16x8 wl = *(const bf16x8*)lo;
      acc[c] = __builtin_amdgcn_mfma_f32_16x16x32_bf16(al, wh, acc[c], 0, 0, 0);
      acc[c] = __builtin_amdgcn_mfma_f32_16x16x32_bf16(ah, wl, acc[c], 0, 0, 0);
      acc[c] = __builtin_amdgcn_mfma_f32_16x16x32_bf16(ah, wh, acc[c], 0, 0, 0);
    }
  }
  if (RELU) {
#pragma unroll
    for (int c = 0; c < 4; ++c)
#pragma unroll
      for (int r = 0; r < 4; ++r) acc[c][r] = fmaxf(acc[c][r], 0.f);
  }
}

__device__ __forceinline__ void commitA(float* xw, int lane, const f32x4 (&acc)[4]) {
  int col15 = lane & 15, hq = lane >> 4;
#pragma unroll
  for (int c = 0; c < 4; ++c)
#pragma unroll
    for (int r = 0; r < 4; ++r) {
      int row = 4 * hq + r, col = 16 * c + col15;
      xw[row * 64 + ((((col >> 2) ^ row) & 15) << 2) + (col & 3)] = acc[c][r];
    }
}

// ---- l2c: 3-layer MLP -> pair merge (K=128, flip) -> 2-layer MLP ----
__global__ void __launch_bounds__(256, 4)
k_l2c(const int* __restrict__ ei, const int* __restrict__ l2ci,
      const float* __restrict__ emb, const float* __restrict__ aggr,
      const unsigned short* __restrict__ WH, const unsigned short* __restrict__ WL,
      const float* __restrict__ l2cb, const float* __restrict__ mb0,
      const float* __restrict__ mb, float* __restrict__ out) {
  __shared__ float xs[4][1024];
  int lane = threadIdx.x & 63, w = threadIdx.x >> 6;
  float* xw = xs[w];
  int rbase = (blockIdx.x * 4 + w) * 16;
  int col15 = lane & 15, hq = lane >> 4;
  int rin = min(rbase + col15, HEDGE - 1);
  int j = l2ci[rin];
  int sN = ei[2 * j], dN = ei[2 * j + 1];
  const float* ap = aggr + (size_t)sN * 64 + 16 * hq;
  const float* ep = emb + (size_t)dN * 64 + 16 * hq;
#pragma unroll
  for (int q = 0; q < 4; ++q) {
    float4 a = *(const float4*)(ap + 4 * q);
    float4 e = *(const float4*)(ep + 4 * q);
    float4 v = {a.x - e.x, a.y - e.y, a.z - e.z, a.w - e.w};
    *(float4*)(xw + col15 * 64 + ((((4 * hq + q) ^ col15) & 15) << 2)) = v;
  }
  f32x4 acc[4];
  mfma_layer<2, true, false>(xw, lane, WH, WL, l2cb, acc);                     commitA(xw, lane, acc);
  mfma_layer<2, true, false>(xw, lane, WH + 4096, WL + 4096, l2cb + 64, acc);  commitA(xw, lane, acc);
  mfma_layer<2, false, false>(xw, lane, WH + 8192, WL + 8192, l2cb + 128, acc); commitA(xw, lane, acc);
  mfma_layer<4, true, true>(xw, lane, WH + 12288, WL + 12288, mb0, acc);       commitA(xw, lane, acc);
  mfma_layer<2, true, false>(xw, lane, WH + 20480, WL + 20480, mb, acc);       commitA(xw, lane, acc);
  mfma_layer<2, false, false>(xw, lane, WH + 24576, WL + 24576, mb + 64, acc);
  int jo[4];
#pragma unroll
  for (int r = 0; r < 4; ++r) {
    int rr = rbase + 4 * hq + r;
    jo[r] = (rr < HEDGE) ? l2ci[rr] : -1;
  }
#pragma unroll
  for (int c = 0; c < 4; ++c)
#pragma unroll
    for (int r = 0; r < 4; ++r)
      if (jo[r] >= 0) out[(size_t)jo[r] * 64 + 16 * c + col15] = acc[c][r];
}

// ---- c2l: 3-layer MLP on (lse[src] - e) ----
__global__ void __launch_bounds__(256, 4)
k_c2l(const int* __restrict__ ei, const int* __restrict__ c2li,
      const float* __restrict__ emb, const float* __restrict__ lse,
      const unsigned short* __restrict__ WH, const unsigned short* __restrict__ WL,
      const float* __restrict__ c2lb, float* __restrict__ out) {
  __shared__ float xs[4][1024];
  int lane = threadIdx.x & 63, w = threadIdx.x >> 6;
  float* xw = xs[w];
  int rbase = (blockIdx.x * 4 + w) * 16;
  int col15 = lane & 15, hq = lane >> 4;
  int rin = min(rbase + col15, HEDGE - 1);
  int j = c2li[rin];
  int sN = ei[2 * j], dN = ei[2 * j + 1];
  const float* ap = lse + (size_t)sN * 64 + 16 * hq;
  const float* ep = emb + (size_t)dN * 64 + 16 * hq;
#pragma unroll
  for (int q = 0; q < 4; ++q) {
    float4 a = *(const float4*)(ap + 4 * q);
    float4 e = *(const float4*)(ep + 4 * q);
    float4 v = {a.x - e.x, a.y - e.y, a.z - e.z, a.w - e.w};
    *(float4*)(xw + col15 * 64 + ((((4 * hq + q) ^ col15) & 15) << 2)) = v;
  }
  f32x4 acc[4];
  mfma_layer<2, true, false>(xw, lane, WH + 28672, WL + 28672, c2lb, acc);       commitA(xw, lane, acc);
  mfma_layer<2, true, false>(xw, lane, WH + 32768, WL + 32768, c2lb + 64, acc);  commitA(xw, lane, acc);
  mfma_layer<2, false, false>(xw, lane, WH + 36864, WL + 36864, c2lb + 128, acc);
  int jo[4];
#pragma unroll
  for (int r = 0; r < 4; ++r) {
    int rr = rbase + 4 * hq + r;
    jo[r] = (rr < HEDGE) ? c2li[rr] : -1;
  }
#pragma unroll
  for (int c = 0; c < 4; ++c)
#pragma unroll
    for (int r = 0; r < 4; ++r)
      if (jo[r] >= 0) out[(size_t)jo[r] * 64 + 16 * c + col15] = acc[c][r];
}

extern "C" void kernel_launch(void* const* d_in, const int* in_sizes, int n_in,
                              void* d_out, int out_size, void* d_ws, size_t ws_size,
                              hipStream_t stream) {
  const int* ei = (const int*)d_in[0];
  const int* l2ci = (const int*)d_in[1];
  const int* c2li = (const int*)d_in[2];
  const float* emb = (const float*)d_in[3];
  const float* l2cW = (const float*)d_in[4];
  const float* l2cb = (const float*)d_in[5];
  const float* c2lW = (const float*)d_in[6];
  const float* c2lb = (const float*)d_in[7];
  const float* mW0 = (const float*)d_in[8];
  const float* mb0 = (const float*)d_in[9];
  const float* mW = (const float*)d_in[10];
  const float* mb = (const float*)d_in[11];
  float* out = (float*)d_out;

  char* ws = (char*)d_ws;
  const size_t NB = (size_t)NNODE * 64 * 4;  // 51.2 MB per node-buffer
  float* aggr = (float*)ws;
  float* lse = (float*)(ws + NB);
  unsigned short* WH = (unsigned short*)(ws + 2 * NB);
  unsigned short* WL = WH + 40960;  // 163840 B total for weights
  char* p = ws + 2 * NB + 163840;
  int* degA = (int*)p; p += NNODE * 4;
  int* degB = (int*)p; p += NNODE * 4;
  int* cursors = (int*)p; p += 2 * 4;
  int* offA = (int*)p; p += NNODE * 4;
  int* offB = (int*)p; p += NNODE * 4;
  int* curA = (int*)p; p += NNODE * 4;
  int* curB = (int*)p; p += NNODE * 4;
  int* listA = (int*)p; p += (size_t)NEDGE * 4;
  int* listB = (int*)p; p += (size_t)HEDGE * 4;

  hipMemsetAsync(degA, 0, (2 * (size_t)NNODE + 2) * 4, stream);  // degA,degB,cursors

  dim3 B(256);
  int gE = (NEDGE + 255) / 256;
  k_deg<<<gE, B, 0, stream>>>(ei, c2li, degA, degB);
  k_alloc<<<(NNODE + 255) / 256, B, 0, stream>>>(degA, offA, curA, degB, offB, curB, cursors);
  k_fill<<<gE, B, 0, stream>>>(ei, c2li, curA, listA, curB, listB);
  k_prepw<<<160, B, 0, stream>>>(l2cW, mW0, mW, c2lW, WH, WL);
  int gN = (NNODE + 3) / 4;
  k_gather<<<2 * gN, B, 0, stream>>>(offA, degA, listA, offB, degB, listB, emb, aggr, lse, gN);
  int gmlp = (HEDGE / 16 + 3) / 4;
  k_l2c<<<gmlp, B, 0, stream>>>(ei, l2ci, emb, aggr, WH, WL, l2cb, mb0, mb, out);
  k_c2l<<<gmlp, B, 0, stream>>>(ei, c2li, emb, lse, WH, WL, c2lb, out);
}

// Round 9
// 736.414 us; speedup vs baseline: 1.0939x; 1.0939x over previous
//
#include <hip/hip_runtime.h>
#include <hip/hip_bf16.h>
#include <math.h>

#define NNODE 200000
#define NEDGE 1000000
#define HEDGE 500000

typedef __attribute__((ext_vector_type(8))) short bf16x8;
typedef __attribute__((ext_vector_type(4))) float f32x4;

// ---- float <-> bf16 (RNE) ----
__device__ __forceinline__ unsigned short f2bf(float f) {  // manual RNE (prep only)
  unsigned u = __float_as_uint(f);
  unsigned r = (u + 0x7fffu + ((u >> 16) & 1u)) >> 16;
  return (unsigned short)r;
}
__device__ __forceinline__ unsigned short f2bf_hw(float f) {  // HW cvt (hot path)
  __hip_bfloat16 h = __float2bfloat16(f);
  return __builtin_bit_cast(unsigned short, h);
}
__device__ __forceinline__ float bf2f(unsigned short h) {
  return __uint_as_float(((unsigned)h) << 16);
}

// ======================= CSR build =======================
__global__ void k_deg(const int* __restrict__ ei, const int* __restrict__ c2li,
                      int* __restrict__ degA, int* __restrict__ degB) {
  int j = blockIdx.x * 256 + threadIdx.x;
  if (j < NEDGE) atomicAdd(&degA[ei[2 * j + 1]], 1);
  if (j < HEDGE) {
    int jj = c2li[j];
    atomicAdd(&degB[ei[2 * jj]], 1);
  }
}

// Wave-aggregated CSR range allocator (bucket order irrelevant for gathers).
__global__ void k_alloc(const int* __restrict__ degA, int* __restrict__ offA, int* __restrict__ curA,
                        const int* __restrict__ degB, int* __restrict__ offB, int* __restrict__ curB,
                        int* __restrict__ cursors) {
  int i = blockIdx.x * 256 + threadIdx.x;
  int lane = threadIdx.x & 63;
  bool act = i < NNODE;
#pragma unroll
  for (int which = 0; which < 2; ++which) {
    const int* deg = which ? degB : degA;
    int* off = which ? offB : offA;
    int* cur = which ? curB : curA;
    int d = act ? deg[i] : 0;
    int incl = d;
#pragma unroll
    for (int s = 1; s < 64; s <<= 1) {
      int v = __shfl_up(incl, s, 64);
      if (lane >= s) incl += v;
    }
    int base = 0;
    if (lane == 63) base = atomicAdd(&cursors[which], incl);
    base = __shfl(base, 63, 64);
    if (act) {
      int o = base + incl - d;
      off[i] = o;
      cur[i] = o;
    }
  }
}

__global__ void k_fill(const int* __restrict__ ei, const int* __restrict__ c2li,
                       int* __restrict__ curA, int* __restrict__ listA,
                       int* __restrict__ curB, int* __restrict__ listB) {
  int j = blockIdx.x * 256 + threadIdx.x;
  if (j < NEDGE) {
    int d = ei[2 * j + 1];
    int s = atomicAdd(&curA[d], 1);
    listA[s] = j;
  }
  if (j < HEDGE) {
    int jj = c2li[j];
    int sn = ei[2 * jj], dn = ei[2 * jj + 1];
    int s = atomicAdd(&curB[sn], 1);
    listB[s] = dn;
  }
}

// ---- fused gather: aggr (task A) + lse (task B), one wave per node ----
// 4x16-lane groups = 4 independent list->row chains per wave; each lane
// loads float4 (16 lanes = full 256B row); cross-group shfl_xor butterfly.
// Task B is TWO-PASS (max pass, then exp-sum pass): round-8 showed the
// online-LSE update is VALU-bound (2 exps + serial rescale per element);
// two-pass is 1 fmax + 1 exp per element with no guarded merges, and the
// pass-2 rows re-hit L1/L2.
__global__ void k_gather(const int* __restrict__ offA, const int* __restrict__ degA,
                         const int* __restrict__ listA,
                         const int* __restrict__ offB, const int* __restrict__ degB,
                         const int* __restrict__ listB,
                         const float* __restrict__ emb,
                         float* __restrict__ aggr, float* __restrict__ lse, int gN) {
  int lane = threadIdx.x & 63, wv = threadIdx.x >> 6;
  int g = lane >> 4, l16 = lane & 15;
  bool taskA = blockIdx.x < gN;
  int node = (taskA ? blockIdx.x : blockIdx.x - gN) * 4 + wv;
  if (node >= NNODE) return;
  if (taskA) {
    int o = offA[node], n = degA[node];
    float sx = 0.f, sy = 0.f, sz = 0.f, sw = 0.f;
    for (int i = g; i < n; i += 4) {
      int e = listA[o + i];
      float4 v = *(const float4*)(emb + (size_t)e * 64 + 4 * l16);
      sx += v.x; sy += v.y; sz += v.z; sw += v.w;
    }
#pragma unroll
    for (int mask = 16; mask <= 32; mask <<= 1) {
      sx += __shfl_xor(sx, mask, 64);
      sy += __shfl_xor(sy, mask, 64);
      sz += __shfl_xor(sz, mask, 64);
      sw += __shfl_xor(sw, mask, 64);
    }
    if (g == 0) {
      float4 v = {sx, sy, sz, sw};
      *(float4*)(aggr + (size_t)node * 64 + 4 * l16) = v;  // empty nodes -> 0
    }
  } else {
    int o = offB[node], n = degB[node];
    if (n == 0) return;  // lse only read at nodes with c2l out-edges
    float mx = -INFINITY, my = -INFINITY, mz = -INFINITY, mw = -INFINITY;
    for (int i = g; i < n; i += 4) {
      int d = listB[o + i];
      float4 v = *(const float4*)(emb + (size_t)d * 64 + 4 * l16);
      mx = fmaxf(mx, v.x); my = fmaxf(my, v.y);
      mz = fmaxf(mz, v.z); mw = fmaxf(mw, v.w);
    }
#pragma unroll
    for (int mask = 16; mask <= 32; mask <<= 1) {
      mx = fmaxf(mx, __shfl_xor(mx, mask, 64));
      my = fmaxf(my, __shfl_xor(my, mask, 64));
      mz = fmaxf(mz, __shfl_xor(mz, mask, 64));
      mw = fmaxf(mw, __shfl_xor(mw, mask, 64));
    }
    float sx = 0.f, sy = 0.f, sz = 0.f, sw = 0.f;
    for (int i = g; i < n; i += 4) {
      int d = listB[o + i];
      float4 v = *(const float4*)(emb + (size_t)d * 64 + 4 * l16);
      sx += __expf(v.x - mx); sy += __expf(v.y - my);
      sz += __expf(v.z - mz); sw += __expf(v.w - mw);
    }
#pragma unroll
    for (int mask = 16; mask <= 32; mask <<= 1) {
      sx += __shfl_xor(sx, mask, 64);
      sy += __shfl_xor(sy, mask, 64);
      sz += __shfl_xor(sz, mask, 64);
      sw += __shfl_xor(sw, mask, 64);
    }
    if (g == 0) {
      float4 v = {__logf(sx) + mx, __logf(sy) + my, __logf(sz) + mz, __logf(sw) + mw};
      *(float4*)(lse + (size_t)node * 64 + 4 * l16) = v;  // s >= 1 (max attained)
    }
  }
}

// ======================= weight prep =======================
// Frag-ordered bf16 hi/lo. value = W[32s + 8*(lane>>4) + j][16c + (lane&15)].
// Elem offsets: l2c L1/L2/L3: 0/4096/8192; merge_W0: 12288 (K=128);
// merge_W L1/L2: 20480/24576; c2l L1/L2/L3: 28672/32768/36864. Total 40960.
__global__ void k_prepw(const float* __restrict__ l2cW, const float* __restrict__ mW0,
                        const float* __restrict__ mW, const float* __restrict__ c2lW,
                        unsigned short* __restrict__ WH, unsigned short* __restrict__ WL) {
  int tid = blockIdx.x * 256 + threadIdx.x;
  if (tid >= 40960) return;
  const float* src;
  int base;
  if (tid < 12288) {
    int m = tid / 4096; src = l2cW + m * 4096; base = m * 4096;
  } else if (tid < 20480) {
    src = mW0; base = 12288;
  } else if (tid < 28672) {
    int m = (tid - 20480) / 4096; src = mW + m * 4096; base = 20480 + m * 4096;
  } else {
    int m = (tid - 28672) / 4096; src = c2lW + m * 4096; base = 28672 + m * 4096;
  }
  int local = tid - base;
  int f = local >> 9;           // frag id = s*4+c
  int l = (local >> 3) & 63;    // lane
  int j = local & 7;            // elem
  int s = f >> 2, c = f & 3;
  int k = 32 * s + 8 * (l >> 4) + j;
  int col = 16 * c + (l & 15);
  float v = src[k * 64 + col];
  unsigned short hh = f2bf(v);
  WH[tid] = hh;
  WL[tid] = f2bf(v - bf2f(hh));
}

// ======================= MFMA MLP machinery =======================
// Wave-private LDS tile xs[16 rows][64 cols] f32, XOR-swizzled:
//   dword(row,col) = row*64 + (((col>>2) ^ row) & 15)*4 + (col & 3)

__device__ __forceinline__ void split8(float t0, float t1, float t2, float t3,
                                       float t4, float t5, float t6, float t7,
                                       bf16x8& ah, bf16x8& al) {
  unsigned short h;
  h = f2bf_hw(t0); ah[0] = (short)h; al[0] = (short)f2bf_hw(t0 - bf2f(h));
  h = f2bf_hw(t1); ah[1] = (short)h; al[1] = (short)f2bf_hw(t1 - bf2f(h));
  h = f2bf_hw(t2); ah[2] = (short)h; al[2] = (short)f2bf_hw(t2 - bf2f(h));
  h = f2bf_hw(t3); ah[3] = (short)h; al[3] = (short)f2bf_hw(t3 - bf2f(h));
  h = f2bf_hw(t4); ah[4] = (short)h; al[4] = (short)f2bf_hw(t4 - bf2f(h));
  h = f2bf_hw(t5); ah[5] = (short)h; al[5] = (short)f2bf_hw(t5 - bf2f(h));
  h = f2bf_hw(t6); ah[6] = (short)h; al[6] = (short)f2bf_hw(t6 - bf2f(h));
  h = f2bf_hw(t7); ah[7] = (short)h; al[7] = (short)f2bf_hw(t7 - bf2f(h));
}

// Split-bf16: acc += al*wh + ah*wl + ah*wh (misses only lo*lo ~ 2^-18).
template <int NS, bool RELU, bool FLIP>
__device__ __forceinline__ void mfma_layer(const float* xw, int lane,
                                           const unsigned short* __restrict__ wh_,
                                           const unsigned short* __restrict__ wl_,
                                           const float* __restrict__ bias, f32x4 (&acc)[4]) {
  int col15 = lane & 15, hq = lane >> 4;
#pragma unroll
  for (int c = 0; c < 4; ++c) {
    float bv = bias[16 * c + col15];
    acc[c] = (f32x4){bv, bv, bv, bv};
  }
#pragma unroll
  for (int s = 0; s < NS; ++s) {
    int flip = (FLIP && s >= NS / 2);
    int arow = flip ? (col15 ^ 1) : col15;
    int ks = flip ? (s - NS / 2) : s;
    const float* xr = xw + arow * 64;
    float4 A0 = *(const float4*)(xr + ((((8 * ks + 2 * hq + 0) ^ arow) & 15) << 2));
    float4 A1 = *(const float4*)(xr + ((((8 * ks + 2 * hq + 1) ^ arow) & 15) << 2));
    bf16x8 ah, al;
    split8(A0.x, A0.y, A0.z, A0.w, A1.x, A1.y, A1.z, A1.w, ah, al);
#pragma unroll
    for (int c = 0; c < 4; ++c) {
      const unsigned short* wo = wh_ + ((size_t)((s * 4 + c) * 64 + lane) * 8);
      const unsigned short* lo = wl_ + ((size_t)((s * 4 + c) * 64 + lane) * 8);
      bf16x8 wh = *(const bf16x8*)wo;
      bf16x8 wl = *(const bf16x8*)lo;
      acc[c] = __builtin_amdgcn_mfma_f32_16x16x32_bf16(al, wh, acc[c], 0, 0, 0);
      acc[c] = __builtin_amdgcn_mfma_f32_16x16x32_bf16(ah, wl, acc[c], 0, 0, 0);
      acc[c] = __builtin_amdgcn_mfma_f32_16x16x32_bf16(ah, wh, acc[c], 0, 0, 0);
    }
  }
  if (RELU) {
#pragma unroll
    for (int c = 0; c < 4; ++c)
#pragma unroll
      for (int r = 0; r < 4; ++r) acc[c][r] = fmaxf(acc[c][r], 0.f);
  }
}

__device__ __forceinline__ void commitA(float* xw, int lane, const f32x4 (&acc)[4]) {
  int col15 = lane & 15, hq = lane >> 4;
#pragma unroll
  for (int c = 0; c < 4; ++c)
#pragma unroll
    for (int r = 0; r < 4; ++r) {
      int row = 4 * hq + r, col = 16 * c + col15;
      xw[row * 64 + ((((col >> 2) ^ row) & 15) << 2) + (col & 3)] = acc[c][r];
    }
}

// ---- l2c: 3-layer MLP -> pair merge (K=128, flip) -> 2-layer MLP ----
__global__ void __launch_bounds__(256, 4)
k_l2c(const int* __restrict__ ei, const int* __restrict__ l2ci,
      const float* __restrict__ emb, const float* __restrict__ aggr,
      const unsigned short* __restrict__ WH, const unsigned short* __restrict__ WL,
      const float* __restrict__ l2cb, const float* __restrict__ mb0,
      const float* __restrict__ mb, float* __restrict__ out) {
  __shared__ float xs[4][1024];
  int lane = threadIdx.x & 63, w = threadIdx.x >> 6;
  float* xw = xs[w];
  int rbase = (blockIdx.x * 4 + w) * 16;
  int col15 = lane & 15, hq = lane >> 4;
  int rin = min(rbase + col15, HEDGE - 1);
  int j = l2ci[rin];
  int sN = ei[2 * j], dN = ei[2 * j + 1];
  const float* ap = aggr + (size_t)sN * 64 + 16 * hq;
  const float* ep = emb + (size_t)dN * 64 + 16 * hq;
#pragma unroll
  for (int q = 0; q < 4; ++q) {
    float4 a = *(const float4*)(ap + 4 * q);
    float4 e = *(const float4*)(ep + 4 * q);
    float4 v = {a.x - e.x, a.y - e.y, a.z - e.z, a.w - e.w};
    *(float4*)(xw + col15 * 64 + ((((4 * hq + q) ^ col15) & 15) << 2)) = v;
  }
  f32x4 acc[4];
  mfma_layer<2, true, false>(xw, lane, WH, WL, l2cb, acc);                     commitA(xw, lane, acc);
  mfma_layer<2, true, false>(xw, lane, WH + 4096, WL + 4096, l2cb + 64, acc);  commitA(xw, lane, acc);
  mfma_layer<2, false, false>(xw, lane, WH + 8192, WL + 8192, l2cb + 128, acc); commitA(xw, lane, acc);
  mfma_layer<4, true, true>(xw, lane, WH + 12288, WL + 12288, mb0, acc);       commitA(xw, lane, acc);
  mfma_layer<2, true, false>(xw, lane, WH + 20480, WL + 20480, mb, acc);       commitA(xw, lane, acc);
  mfma_layer<2, false, false>(xw, lane, WH + 24576, WL + 24576, mb + 64, acc);
  int jo[4];
#pragma unroll
  for (int r = 0; r < 4; ++r) {
    int rr = rbase + 4 * hq + r;
    jo[r] = (rr < HEDGE) ? l2ci[rr] : -1;
  }
#pragma unroll
  for (int c = 0; c < 4; ++c)
#pragma unroll
    for (int r = 0; r < 4; ++r)
      if (jo[r] >= 0) out[(size_t)jo[r] * 64 + 16 * c + col15] = acc[c][r];
}

// ---- c2l: 3-layer MLP on (lse[src] - e) ----
__global__ void __launch_bounds__(256, 4)
k_c2l(const int* __restrict__ ei, const int* __restrict__ c2li,
      const float* __restrict__ emb, const float* __restrict__ lse,
      const unsigned short* __restrict__ WH, const unsigned short* __restrict__ WL,
      const float* __restrict__ c2lb, float* __restrict__ out) {
  __shared__ float xs[4][1024];
  int lane = threadIdx.x & 63, w = threadIdx.x >> 6;
  float* xw = xs[w];
  int rbase = (blockIdx.x * 4 + w) * 16;
  int col15 = lane & 15, hq = lane >> 4;
  int rin = min(rbase + col15, HEDGE - 1);
  int j = c2li[rin];
  int sN = ei[2 * j], dN = ei[2 * j + 1];
  const float* ap = lse + (size_t)sN * 64 + 16 * hq;
  const float* ep = emb + (size_t)dN * 64 + 16 * hq;
#pragma unroll
  for (int q = 0; q < 4; ++q) {
    float4 a = *(const float4*)(ap + 4 * q);
    float4 e = *(const float4*)(ep + 4 * q);
    float4 v = {a.x - e.x, a.y - e.y, a.z - e.z, a.w - e.w};
    *(float4*)(xw + col15 * 64 + ((((4 * hq + q) ^ col15) & 15) << 2)) = v;
  }
  f32x4 acc[4];
  mfma_layer<2, true, false>(xw, lane, WH + 28672, WL + 28672, c2lb, acc);       commitA(xw, lane, acc);
  mfma_layer<2, true, false>(xw, lane, WH + 32768, WL + 32768, c2lb + 64, acc);  commitA(xw, lane, acc);
  mfma_layer<2, false, false>(xw, lane, WH + 36864, WL + 36864, c2lb + 128, acc);
  int jo[4];
#pragma unroll
  for (int r = 0; r < 4; ++r) {
    int rr = rbase + 4 * hq + r;
    jo[r] = (rr < HEDGE) ? c2li[rr] : -1;
  }
#pragma unroll
  for (int c = 0; c < 4; ++c)
#pragma unroll
    for (int r = 0; r < 4; ++r)
      if (jo[r] >= 0) out[(size_t)jo[r] * 64 + 16 * c + col15] = acc[c][r];
}

extern "C" void kernel_launch(void* const* d_in, const int* in_sizes, int n_in,
                              void* d_out, int out_size, void* d_ws, size_t ws_size,
                              hipStream_t stream) {
  const int* ei = (const int*)d_in[0];
  const int* l2ci = (const int*)d_in[1];
  const int* c2li = (const int*)d_in[2];
  const float* emb = (const float*)d_in[3];
  const float* l2cW = (const float*)d_in[4];
  const float* l2cb = (const float*)d_in[5];
  const float* c2lW = (const float*)d_in[6];
  const float* c2lb = (const float*)d_in[7];
  const float* mW0 = (const float*)d_in[8];
  const float* mb0 = (const float*)d_in[9];
  const float* mW = (const float*)d_in[10];
  const float* mb = (const float*)d_in[11];
  float* out = (float*)d_out;

  char* ws = (char*)d_ws;
  const size_t NB = (size_t)NNODE * 64 * 4;  // 51.2 MB per node-buffer
  float* aggr = (float*)ws;
  float* lse = (float*)(ws + NB);
  unsigned short* WH = (unsigned short*)(ws + 2 * NB);
  unsigned short* WL = WH + 40960;  // 163840 B total for weights
  char* p = ws + 2 * NB + 163840;
  int* degA = (int*)p; p += NNODE * 4;
  int* degB = (int*)p; p += NNODE * 4;
  int* cursors = (int*)p; p += 2 * 4;
  int* offA = (int*)p; p += NNODE * 4;
  int* offB = (int*)p; p += NNODE * 4;
  int* curA = (int*)p; p += NNODE * 4;
  int* curB = (int*)p; p += NNODE * 4;
  int* listA = (int*)p; p += (size_t)NEDGE * 4;
  int* listB = (int*)p; p += (size_t)HEDGE * 4;

  hipMemsetAsync(degA, 0, (2 * (size_t)NNODE + 2) * 4, stream);  // degA,degB,cursors

  dim3 B(256);
  int gE = (NEDGE + 255) / 256;
  k_deg<<<gE, B, 0, stream>>>(ei, c2li, degA, degB);
  k_alloc<<<(NNODE + 255) / 256, B, 0, stream>>>(degA, offA, curA, degB, offB, curB, cursors);
  k_fill<<<gE, B, 0, stream>>>(ei, c2li, curA, listA, curB, listB);
  k_prepw<<<160, B, 0, stream>>>(l2cW, mW0, mW, c2lW, WH, WL);
  int gN = (NNODE + 3) / 4;
  k_gather<<<2 * gN, B, 0, stream>>>(offA, degA, listA, offB, degB, listB, emb, aggr, lse, gN);
  int gmlp = (HEDGE / 16 + 3) / 4;
  k_l2c<<<gmlp, B, 0, stream>>>(ei, l2ci, emb, aggr, WH, WL, l2cb, mb0, mb, out);
  k_c2l<<<gmlp, B, 0, stream>>>(ei, c2li, emb, lse, WH, WL, c2lb, out);
}

// Round 10
// 640.907 us; speedup vs baseline: 1.2569x; 1.1490x over previous
//
#include <hip/hip_runtime.h>
#include <hip/hip_bf16.h>
#include <math.h>

#define NNODE 200000
#define NEDGE 1000000
#define HEDGE 500000

typedef __attribute__((ext_vector_type(8))) short bf16x8;
typedef __attribute__((ext_vector_type(4))) float f32x4;

// ---- float <-> bf16 (RNE) ----
__device__ __forceinline__ unsigned short f2bf(float f) {  // manual RNE (prep only)
  unsigned u = __float_as_uint(f);
  unsigned r = (u + 0x7fffu + ((u >> 16) & 1u)) >> 16;
  return (unsigned short)r;
}
__device__ __forceinline__ unsigned short f2bf_hw(float f) {  // HW cvt (hot path)
  __hip_bfloat16 h = __float2bfloat16(f);
  return __builtin_bit_cast(unsigned short, h);
}
__device__ __forceinline__ float bf2f(unsigned short h) {
  return __uint_as_float(((unsigned)h) << 16);
}

// ======================= CSR build =======================
__global__ void k_deg(const int* __restrict__ ei, const int* __restrict__ c2li,
                      int* __restrict__ degA, int* __restrict__ degB) {
  int j = blockIdx.x * 256 + threadIdx.x;
  if (j < NEDGE) atomicAdd(&degA[ei[2 * j + 1]], 1);
  if (j < HEDGE) {
    int jj = c2li[j];
    atomicAdd(&degB[ei[2 * jj]], 1);
  }
}

// Wave-aggregated CSR range allocator (bucket order irrelevant for gathers).
__global__ void k_alloc(const int* __restrict__ degA, int* __restrict__ offA, int* __restrict__ curA,
                        const int* __restrict__ degB, int* __restrict__ offB, int* __restrict__ curB,
                        int* __restrict__ cursors) {
  int i = blockIdx.x * 256 + threadIdx.x;
  int lane = threadIdx.x & 63;
  bool act = i < NNODE;
#pragma unroll
  for (int which = 0; which < 2; ++which) {
    const int* deg = which ? degB : degA;
    int* off = which ? offB : offA;
    int* cur = which ? curB : curA;
    int d = act ? deg[i] : 0;
    int incl = d;
#pragma unroll
    for (int s = 1; s < 64; s <<= 1) {
      int v = __shfl_up(incl, s, 64);
      if (lane >= s) incl += v;
    }
    int base = 0;
    if (lane == 63) base = atomicAdd(&cursors[which], incl);
    base = __shfl(base, 63, 64);
    if (act) {
      int o = base + incl - d;
      off[i] = o;
      cur[i] = o;
    }
  }
}

__global__ void k_fill(const int* __restrict__ ei, const int* __restrict__ c2li,
                       int* __restrict__ curA, int* __restrict__ listA,
                       int* __restrict__ curB, int* __restrict__ listB) {
  int j = blockIdx.x * 256 + threadIdx.x;
  if (j < NEDGE) {
    int d = ei[2 * j + 1];
    int s = atomicAdd(&curA[d], 1);
    listA[s] = j;
  }
  if (j < HEDGE) {
    int jj = c2li[j];
    int sn = ei[2 * jj], dn = ei[2 * jj + 1];
    int s = atomicAdd(&curB[sn], 1);
    listB[s] = dn;
  }
}

// ---- fused gather: aggr (task A) + lse (task B), one wave per node ----
// 4x16-lane groups x 2 unroll slots = 8 independent list->row chains/wave
// (round-9: 4 chains, VALU 34%, HBM 17% -> latency-bound; slot merges are
// now PLAIN fmax/add so the round-8 VALU blowup doesn't recur).
// Task B fast path (n<=8, ~99% of nodes): rows register-cached, exp pass
// needs no reload; exp(-inf - m) = 0 handles empty slots branch-free.
__global__ void k_gather(const int* __restrict__ offA, const int* __restrict__ degA,
                         const int* __restrict__ listA,
                         const int* __restrict__ offB, const int* __restrict__ degB,
                         const int* __restrict__ listB,
                         const float* __restrict__ emb,
                         float* __restrict__ aggr, float* __restrict__ lse, int gN) {
  int lane = threadIdx.x & 63, wv = threadIdx.x >> 6;
  int g = lane >> 4, l16 = lane & 15;
  bool taskA = blockIdx.x < gN;
  int node = (taskA ? blockIdx.x : blockIdx.x - gN) * 4 + wv;
  if (node >= NNODE) return;
  if (taskA) {
    int o = offA[node], n = degA[node];
    float4 s0 = {0.f, 0.f, 0.f, 0.f}, s1 = {0.f, 0.f, 0.f, 0.f};
    for (int i0 = 0; i0 < n; i0 += 8) {
      int ia = i0 + g, ib = i0 + 4 + g;
      int ea = (ia < n) ? listA[o + ia] : -1;
      int eb = (ib < n) ? listA[o + ib] : -1;
      if (ea >= 0) {
        float4 v = *(const float4*)(emb + (size_t)ea * 64 + 4 * l16);
        s0.x += v.x; s0.y += v.y; s0.z += v.z; s0.w += v.w;
      }
      if (eb >= 0) {
        float4 v = *(const float4*)(emb + (size_t)eb * 64 + 4 * l16);
        s1.x += v.x; s1.y += v.y; s1.z += v.z; s1.w += v.w;
      }
    }
    float sx = s0.x + s1.x, sy = s0.y + s1.y, sz = s0.z + s1.z, sw = s0.w + s1.w;
#pragma unroll
    for (int mask = 16; mask <= 32; mask <<= 1) {
      sx += __shfl_xor(sx, mask, 64);
      sy += __shfl_xor(sy, mask, 64);
      sz += __shfl_xor(sz, mask, 64);
      sw += __shfl_xor(sw, mask, 64);
    }
    if (g == 0) {
      float4 v = {sx, sy, sz, sw};
      *(float4*)(aggr + (size_t)node * 64 + 4 * l16) = v;  // empty nodes -> 0
    }
  } else {
    int o = offB[node], n = degB[node];
    if (n == 0) return;  // lse only read at nodes with c2l out-edges
    float mx, my, mz, mw, sx, sy, sz, sw;
    if (n <= 8) {
      // register-cached fast path: one memory round per group
      int ea = (g < n) ? listB[o + g] : -1;
      int eb = (4 + g < n) ? listB[o + 4 + g] : -1;
      float4 v0 = {-INFINITY, -INFINITY, -INFINITY, -INFINITY}, v1 = v0;
      if (ea >= 0) v0 = *(const float4*)(emb + (size_t)ea * 64 + 4 * l16);
      if (eb >= 0) v1 = *(const float4*)(emb + (size_t)eb * 64 + 4 * l16);
      mx = fmaxf(v0.x, v1.x); my = fmaxf(v0.y, v1.y);
      mz = fmaxf(v0.z, v1.z); mw = fmaxf(v0.w, v1.w);
#pragma unroll
      for (int mask = 16; mask <= 32; mask <<= 1) {
        mx = fmaxf(mx, __shfl_xor(mx, mask, 64));
        my = fmaxf(my, __shfl_xor(my, mask, 64));
        mz = fmaxf(mz, __shfl_xor(mz, mask, 64));
        mw = fmaxf(mw, __shfl_xor(mw, mask, 64));
      }
      sx = __expf(v0.x - mx) + __expf(v1.x - mx);
      sy = __expf(v0.y - my) + __expf(v1.y - my);
      sz = __expf(v0.z - mz) + __expf(v1.z - mz);
      sw = __expf(v0.w - mw) + __expf(v1.w - mw);
    } else {
      // two-pass fallback (rare high-degree nodes)
      mx = my = mz = mw = -INFINITY;
      for (int i0 = 0; i0 < n; i0 += 8) {
        int ia = i0 + g, ib = i0 + 4 + g;
        int ea = (ia < n) ? listB[o + ia] : -1;
        int eb = (ib < n) ? listB[o + ib] : -1;
        if (ea >= 0) {
          float4 v = *(const float4*)(emb + (size_t)ea * 64 + 4 * l16);
          mx = fmaxf(mx, v.x); my = fmaxf(my, v.y);
          mz = fmaxf(mz, v.z); mw = fmaxf(mw, v.w);
        }
        if (eb >= 0) {
          float4 v = *(const float4*)(emb + (size_t)eb * 64 + 4 * l16);
          mx = fmaxf(mx, v.x); my = fmaxf(my, v.y);
          mz = fmaxf(mz, v.z); mw = fmaxf(mw, v.w);
        }
      }
#pragma unroll
      for (int mask = 16; mask <= 32; mask <<= 1) {
        mx = fmaxf(mx, __shfl_xor(mx, mask, 64));
        my = fmaxf(my, __shfl_xor(my, mask, 64));
        mz = fmaxf(mz, __shfl_xor(mz, mask, 64));
        mw = fmaxf(mw, __shfl_xor(mw, mask, 64));
      }
      sx = sy = sz = sw = 0.f;
      for (int i0 = 0; i0 < n; i0 += 8) {
        int ia = i0 + g, ib = i0 + 4 + g;
        int ea = (ia < n) ? listB[o + ia] : -1;
        int eb = (ib < n) ? listB[o + ib] : -1;
        if (ea >= 0) {
          float4 v = *(const float4*)(emb + (size_t)ea * 64 + 4 * l16);
          sx += __expf(v.x - mx); sy += __expf(v.y - my);
          sz += __expf(v.z - mz); sw += __expf(v.w - mw);
        }
        if (eb >= 0) {
          float4 v = *(const float4*)(emb + (size_t)eb * 64 + 4 * l16);
          sx += __expf(v.x - mx); sy += __expf(v.y - my);
          sz += __expf(v.z - mz); sw += __expf(v.w - mw);
        }
      }
    }
#pragma unroll
    for (int mask = 16; mask <= 32; mask <<= 1) {
      sx += __shfl_xor(sx, mask, 64);
      sy += __shfl_xor(sy, mask, 64);
      sz += __shfl_xor(sz, mask, 64);
      sw += __shfl_xor(sw, mask, 64);
    }
    if (g == 0) {
      float4 v = {__logf(sx) + mx, __logf(sy) + my, __logf(sz) + mz, __logf(sw) + mw};
      *(float4*)(lse + (size_t)node * 64 + 4 * l16) = v;  // s >= 1 (max attained)
    }
  }
}

// ======================= weight prep =======================
// Frag-ordered bf16 hi/lo. value = W[32s + 8*(lane>>4) + j][16c + (lane&15)].
// Elem offsets: l2c L1/L2/L3: 0/4096/8192; merge_W0: 12288 (K=128);
// merge_W L1/L2: 20480/24576; c2l L1/L2/L3: 28672/32768/36864. Total 40960.
__global__ void k_prepw(const float* __restrict__ l2cW, const float* __restrict__ mW0,
                        const float* __restrict__ mW, const float* __restrict__ c2lW,
                        unsigned short* __restrict__ WH, unsigned short* __restrict__ WL) {
  int tid = blockIdx.x * 256 + threadIdx.x;
  if (tid >= 40960) return;
  const float* src;
  int base;
  if (tid < 12288) {
    int m = tid / 4096; src = l2cW + m * 4096; base = m * 4096;
  } else if (tid < 20480) {
    src = mW0; base = 12288;
  } else if (tid < 28672) {
    int m = (tid - 20480) / 4096; src = mW + m * 4096; base = 20480 + m * 4096;
  } else {
    int m = (tid - 28672) / 4096; src = c2lW + m * 4096; base = 28672 + m * 4096;
  }
  int local = tid - base;
  int f = local >> 9;           // frag id = s*4+c
  int l = (local >> 3) & 63;    // lane
  int j = local & 7;            // elem
  int s = f >> 2, c = f & 3;
  int k = 32 * s + 8 * (l >> 4) + j;
  int col = 16 * c + (l & 15);
  float v = src[k * 64 + col];
  unsigned short hh = f2bf(v);
  WH[tid] = hh;
  WL[tid] = f2bf(v - bf2f(hh));
}

// ======================= MFMA MLP machinery =======================
// Wave-private LDS tile xs[16 rows][64 cols] f32, XOR-swizzled:
//   dword(row,col) = row*64 + (((col>>2) ^ row) & 15)*4 + (col & 3)
// Weights are staged per-layer into block-shared LDS (16 KB hi+lo):
// round-9 analysis: each wave streamed 112 KB of weights from L2 per 16
// edges (~3.5 GB total) -> that, not MFMA, dominated the MLP kernels.

__device__ __forceinline__ void split8(float t0, float t1, float t2, float t3,
                                       float t4, float t5, float t6, float t7,
                                       bf16x8& ah, bf16x8& al) {
  unsigned short h;
  h = f2bf_hw(t0); ah[0] = (short)h; al[0] = (short)f2bf_hw(t0 - bf2f(h));
  h = f2bf_hw(t1); ah[1] = (short)h; al[1] = (short)f2bf_hw(t1 - bf2f(h));
  h = f2bf_hw(t2); ah[2] = (short)h; al[2] = (short)f2bf_hw(t2 - bf2f(h));
  h = f2bf_hw(t3); ah[3] = (short)h; al[3] = (short)f2bf_hw(t3 - bf2f(h));
  h = f2bf_hw(t4); ah[4] = (short)h; al[4] = (short)f2bf_hw(t4 - bf2f(h));
  h = f2bf_hw(t5); ah[5] = (short)h; al[5] = (short)f2bf_hw(t5 - bf2f(h));
  h = f2bf_hw(t6); ah[6] = (short)h; al[6] = (short)f2bf_hw(t6 - bf2f(h));
  h = f2bf_hw(t7); ah[7] = (short)h; al[7] = (short)f2bf_hw(t7 - bf2f(h));
}

// Stage 4096 weight elems (hi+lo, 8 KB each) global->LDS, block-cooperative.
__device__ __forceinline__ void stage_w(const unsigned short* __restrict__ WH,
                                        const unsigned short* __restrict__ WL, int off,
                                        unsigned short* lwh, unsigned short* lwl, int tid) {
  __syncthreads();  // all waves done reading previous layer's weights
  const uint4* gh = (const uint4*)(WH + off);
  const uint4* gl = (const uint4*)(WL + off);
  uint4* sh = (uint4*)lwh;
  uint4* sl = (uint4*)lwl;
#pragma unroll
  for (int t = 0; t < 2; ++t) {
    int i = tid + 256 * t;  // 512 uint4 per array
    sh[i] = gh[i];
    sl[i] = gl[i];
  }
  __syncthreads();
}

__device__ __forceinline__ void acc_init(const float* __restrict__ bias, int col15,
                                         f32x4 (&acc)[4]) {
#pragma unroll
  for (int c = 0; c < 4; ++c) {
    float bv = bias[16 * c + col15];
    acc[c] = (f32x4){bv, bv, bv, bv};
  }
}

__device__ __forceinline__ void acc_relu(f32x4 (&acc)[4]) {
#pragma unroll
  for (int c = 0; c < 4; ++c)
#pragma unroll
    for (int r = 0; r < 4; ++r) acc[c][r] = fmaxf(acc[c][r], 0.f);
}

// Accumulate NS K-slices from LDS weights. FLIPALL: read partner row (t^1).
// Split-bf16: acc += al*wh + ah*wl + ah*wh (misses only lo*lo ~ 2^-18).
template <int NS, bool FLIPALL>
__device__ __forceinline__ void mfma_accum(const float* xw, int lane,
                                           const unsigned short* lwh,
                                           const unsigned short* lwl, f32x4 (&acc)[4]) {
  int col15 = lane & 15, hq = lane >> 4;
  int arow = FLIPALL ? (col15 ^ 1) : col15;
  const float* xr = xw + arow * 64;
#pragma unroll
  for (int s = 0; s < NS; ++s) {
    float4 A0 = *(const float4*)(xr + ((((8 * s + 2 * hq + 0) ^ arow) & 15) << 2));
    float4 A1 = *(const float4*)(xr + ((((8 * s + 2 * hq + 1) ^ arow) & 15) << 2));
    bf16x8 ah, al;
    split8(A0.x, A0.y, A0.z, A0.w, A1.x, A1.y, A1.z, A1.w, ah, al);
#pragma unroll
    for (int c = 0; c < 4; ++c) {
      bf16x8 wh = *(const bf16x8*)(lwh + ((s * 4 + c) * 64 + lane) * 8);
      bf16x8 wl = *(const bf16x8*)(lwl + ((s * 4 + c) * 64 + lane) * 8);
      acc[c] = __builtin_amdgcn_mfma_f32_16x16x32_bf16(al, wh, acc[c], 0, 0, 0);
      acc[c] = __builtin_amdgcn_mfma_f32_16x16x32_bf16(ah, wl, acc[c], 0, 0, 0);
      acc[c] = __builtin_amdgcn_mfma_f32_16x16x32_bf16(ah, wh, acc[c], 0, 0, 0);
    }
  }
}

__device__ __forceinline__ void commitA(float* xw, int lane, const f32x4 (&acc)[4]) {
  int col15 = lane & 15, hq = lane >> 4;
#pragma unroll
  for (int c = 0; c < 4; ++c)
#pragma unroll
    for (int r = 0; r < 4; ++r) {
      int row = 4 * hq + r, col = 16 * c + col15;
      xw[row * 64 + ((((col >> 2) ^ row) & 15) << 2) + (col & 3)] = acc[c][r];
    }
}

// ---- l2c: 3-layer MLP -> pair merge (K=128, staged as 2 halves) -> 2-layer MLP ----
__global__ void __launch_bounds__(256, 4)
k_l2c(const int* __restrict__ ei, const int* __restrict__ l2ci,
      const float* __restrict__ emb, const float* __restrict__ aggr,
      const unsigned short* __restrict__ WH, const unsigned short* __restrict__ WL,
      const float* __restrict__ l2cb, const float* __restrict__ mb0,
      const float* __restrict__ mb, float* __restrict__ out) {
  __shared__ float xs[4][1024];
  __shared__ unsigned short lwh[4096];
  __shared__ unsigned short lwl[4096];
  int tid = threadIdx.x;
  int lane = tid & 63, w = tid >> 6;
  float* xw = xs[w];
  int rbase = (blockIdx.x * 4 + w) * 16;
  int col15 = lane & 15, hq = lane >> 4;
  int rin = min(rbase + col15, HEDGE - 1);
  int j = l2ci[rin];
  int sN = ei[2 * j], dN = ei[2 * j + 1];
  const float* ap = aggr + (size_t)sN * 64 + 16 * hq;
  const float* ep = emb + (size_t)dN * 64 + 16 * hq;
#pragma unroll
  for (int q = 0; q < 4; ++q) {
    float4 a = *(const float4*)(ap + 4 * q);
    float4 e = *(const float4*)(ep + 4 * q);
    float4 v = {a.x - e.x, a.y - e.y, a.z - e.z, a.w - e.w};
    *(float4*)(xw + col15 * 64 + ((((4 * hq + q) ^ col15) & 15) << 2)) = v;
  }
  f32x4 acc[4];
  stage_w(WH, WL, 0, lwh, lwl, tid);
  acc_init(l2cb, col15, acc);       mfma_accum<2, false>(xw, lane, lwh, lwl, acc);
  acc_relu(acc);                    commitA(xw, lane, acc);
  stage_w(WH, WL, 4096, lwh, lwl, tid);
  acc_init(l2cb + 64, col15, acc);  mfma_accum<2, false>(xw, lane, lwh, lwl, acc);
  acc_relu(acc);                    commitA(xw, lane, acc);
  stage_w(WH, WL, 8192, lwh, lwl, tid);
  acc_init(l2cb + 128, col15, acc); mfma_accum<2, false>(xw, lane, lwh, lwl, acc);
  commitA(xw, lane, acc);           // msg
  stage_w(WH, WL, 12288, lwh, lwl, tid);   // merge own-half (K rows 0..63)
  acc_init(mb0, col15, acc);        mfma_accum<2, false>(xw, lane, lwh, lwl, acc);
  stage_w(WH, WL, 16384, lwh, lwl, tid);   // merge flip-half (partner msg)
  mfma_accum<2, true>(xw, lane, lwh, lwl, acc);
  acc_relu(acc);                    commitA(xw, lane, acc);
  stage_w(WH, WL, 20480, lwh, lwl, tid);
  acc_init(mb, col15, acc);         mfma_accum<2, false>(xw, lane, lwh, lwl, acc);
  acc_relu(acc);                    commitA(xw, lane, acc);
  stage_w(WH, WL, 24576, lwh, lwl, tid);
  acc_init(mb + 64, col15, acc);    mfma_accum<2, false>(xw, lane, lwh, lwl, acc);
  int jo[4];
#pragma unroll
  for (int r = 0; r < 4; ++r) {
    int rr = rbase + 4 * hq + r;
    jo[r] = (rr < HEDGE) ? l2ci[rr] : -1;
  }
#pragma unroll
  for (int c = 0; c < 4; ++c)
#pragma unroll
    for (int r = 0; r < 4; ++r)
      if (jo[r] >= 0) out[(size_t)jo[r] * 64 + 16 * c + col15] = acc[c][r];
}

// ---- c2l: 3-layer MLP on (lse[src] - e) ----
__global__ void __launch_bounds__(256, 4)
k_c2l(const int* __restrict__ ei, const int* __restrict__ c2li,
      const float* __restrict__ emb, const float* __restrict__ lse,
      const unsigned short* __restrict__ WH, const unsigned short* __restrict__ WL,
      const float* __restrict__ c2lb, float* __restrict__ out) {
  __shared__ float xs[4][1024];
  __shared__ unsigned short lwh[4096];
  __shared__ unsigned short lwl[4096];
  int tid = threadIdx.x;
  int lane = tid & 63, w = tid >> 6;
  float* xw = xs[w];
  int rbase = (blockIdx.x * 4 + w) * 16;
  int col15 = lane & 15, hq = lane >> 4;
  int rin = min(rbase + col15, HEDGE - 1);
  int j = c2li[rin];
  int sN = ei[2 * j], dN = ei[2 * j + 1];
  const float* ap = lse + (size_t)sN * 64 + 16 * hq;
  const float* ep = emb + (size_t)dN * 64 + 16 * hq;
#pragma unroll
  for (int q = 0; q < 4; ++q) {
    float4 a = *(const float4*)(ap + 4 * q);
    float4 e = *(const float4*)(ep + 4 * q);
    float4 v = {a.x - e.x, a.y - e.y, a.z - e.z, a.w - e.w};
    *(float4*)(xw + col15 * 64 + ((((4 * hq + q) ^ col15) & 15) << 2)) = v;
  }
  f32x4 acc[4];
  stage_w(WH, WL, 28672, lwh, lwl, tid);
  acc_init(c2lb, col15, acc);       mfma_accum<2, false>(xw, lane, lwh, lwl, acc);
  acc_relu(acc);                    commitA(xw, lane, acc);
  stage_w(WH, WL, 32768, lwh, lwl, tid);
  acc_init(c2lb + 64, col15, acc);  mfma_accum<2, false>(xw, lane, lwh, lwl, acc);
  acc_relu(acc);                    commitA(xw, lane, acc);
  stage_w(WH, WL, 36864, lwh, lwl, tid);
  acc_init(c2lb + 128, col15, acc); mfma_accum<2, false>(xw, lane, lwh, lwl, acc);
  int jo[4];
#pragma unroll
  for (int r = 0; r < 4; ++r) {
    int rr = rbase + 4 * hq + r;
    jo[r] = (rr < HEDGE) ? c2li[rr] : -1;
  }
#pragma unroll
  for (int c = 0; c < 4; ++c)
#pragma unroll
    for (int r = 0; r < 4; ++r)
      if (jo[r] >= 0) out[(size_t)jo[r] * 64 + 16 * c + col15] = acc[c][r];
}

extern "C" void kernel_launch(void* const* d_in, const int* in_sizes, int n_in,
                              void* d_out, int out_size, void* d_ws, size_t ws_size,
                              hipStream_t stream) {
  const int* ei = (const int*)d_in[0];
  const int* l2ci = (const int*)d_in[1];
  const int* c2li = (const int*)d_in[2];
  const float* emb = (const float*)d_in[3];
  const float* l2cW = (const float*)d_in[4];
  const float* l2cb = (const float*)d_in[5];
  const float* c2lW = (const float*)d_in[6];
  const float* c2lb = (const float*)d_in[7];
  const float* mW0 = (const float*)d_in[8];
  const float* mb0 = (const float*)d_in[9];
  const float* mW = (const float*)d_in[10];
  const float* mb = (const float*)d_in[11];
  float* out = (float*)d_out;

  char* ws = (char*)d_ws;
  const size_t NB = (size_t)NNODE * 64 * 4;  // 51.2 MB per node-buffer
  float* aggr = (float*)ws;
  float* lse = (float*)(ws + NB);
  unsigned short* WH = (unsigned short*)(ws + 2 * NB);
  unsigned short* WL = WH + 40960;  // 163840 B total for weights
  char* p = ws + 2 * NB + 163840;
  int* degA = (int*)p; p += NNODE * 4;
  int* degB = (int*)p; p += NNODE * 4;
  int* cursors = (int*)p; p += 2 * 4;
  int* offA = (int*)p; p += NNODE * 4;
  int* offB = (int*)p; p += NNODE * 4;
  int* curA = (int*)p; p += NNODE * 4;
  int* curB = (int*)p; p += NNODE * 4;
  int* listA = (int*)p; p += (size_t)NEDGE * 4;
  int* listB = (int*)p; p += (size_t)HEDGE * 4;

  hipMemsetAsync(degA, 0, (2 * (size_t)NNODE + 2) * 4, stream);  // degA,degB,cursors

  dim3 B(256);
  int gE = (NEDGE + 255) / 256;
  k_deg<<<gE, B, 0, stream>>>(ei, c2li, degA, degB);
  k_alloc<<<(NNODE + 255) / 256, B, 0, stream>>>(degA, offA, curA, degB, offB, curB, cursors);
  k_fill<<<gE, B, 0, stream>>>(ei, c2li, curA, listA, curB, listB);
  k_prepw<<<160, B, 0, stream>>>(l2cW, mW0, mW, c2lW, WH, WL);
  int gN = (NNODE + 3) / 4;
  k_gather<<<2 * gN, B, 0, stream>>>(offA, degA, listA, offB, degB, listB, emb, aggr, lse, gN);
  int gmlp = (HEDGE / 16 + 3) / 4;
  k_l2c<<<gmlp, B, 0, stream>>>(ei, l2ci, emb, aggr, WH, WL, l2cb, mb0, mb, out);
  k_c2l<<<gmlp, B, 0, stream>>>(ei, c2li, emb, lse, WH, WL, c2lb, out);
}

// Round 11
// 575.930 us; speedup vs baseline: 1.3987x; 1.1128x over previous
//
#include <hip/hip_runtime.h>
#include <hip/hip_bf16.h>
#include <math.h>

#define NNODE 200000
#define NEDGE 1000000
#define HEDGE 500000

typedef __attribute__((ext_vector_type(8))) short bf16x8;
typedef __attribute__((ext_vector_type(4))) float f32x4;

// ---- float <-> bf16 (RNE) ----
__device__ __forceinline__ unsigned short f2bf(float f) {  // manual RNE (prep only)
  unsigned u = __float_as_uint(f);
  unsigned r = (u + 0x7fffu + ((u >> 16) & 1u)) >> 16;
  return (unsigned short)r;
}
__device__ __forceinline__ unsigned short f2bf_hw(float f) {  // HW cvt (hot path)
  __hip_bfloat16 h = __float2bfloat16(f);
  return __builtin_bit_cast(unsigned short, h);
}
__device__ __forceinline__ float bf2f(unsigned short h) {
  return __uint_as_float(((unsigned)h) << 16);
}

// ======================= CSR build =======================
__global__ void k_deg(const int* __restrict__ ei, const int* __restrict__ c2li,
                      int* __restrict__ degA, int* __restrict__ degB) {
  int j = blockIdx.x * 256 + threadIdx.x;
  if (j < NEDGE) atomicAdd(&degA[ei[2 * j + 1]], 1);
  if (j < HEDGE) {
    int jj = c2li[j];
    atomicAdd(&degB[ei[2 * jj]], 1);
  }
}

// Wave-aggregated CSR range allocator (bucket order irrelevant for gathers).
__global__ void k_alloc(const int* __restrict__ degA, int* __restrict__ offA, int* __restrict__ curA,
                        const int* __restrict__ degB, int* __restrict__ offB, int* __restrict__ curB,
                        int* __restrict__ cursors) {
  int i = blockIdx.x * 256 + threadIdx.x;
  int lane = threadIdx.x & 63;
  bool act = i < NNODE;
#pragma unroll
  for (int which = 0; which < 2; ++which) {
    const int* deg = which ? degB : degA;
    int* off = which ? offB : offA;
    int* cur = which ? curB : curA;
    int d = act ? deg[i] : 0;
    int incl = d;
#pragma unroll
    for (int s = 1; s < 64; s <<= 1) {
      int v = __shfl_up(incl, s, 64);
      if (lane >= s) incl += v;
    }
    int base = 0;
    if (lane == 63) base = atomicAdd(&cursors[which], incl);
    base = __shfl(base, 63, 64);
    if (act) {
      int o = base + incl - d;
      off[i] = o;
      cur[i] = o;
    }
  }
}

__global__ void k_fill(const int* __restrict__ ei, const int* __restrict__ c2li,
                       int* __restrict__ curA, int* __restrict__ listA,
                       int* __restrict__ curB, int* __restrict__ listB) {
  int j = blockIdx.x * 256 + threadIdx.x;
  if (j < NEDGE) {
    int d = ei[2 * j + 1];
    int s = atomicAdd(&curA[d], 1);
    listA[s] = j;
  }
  if (j < HEDGE) {
    int jj = c2li[j];
    int sn = ei[2 * jj], dn = ei[2 * jj + 1];
    int s = atomicAdd(&curB[sn], 1);
    listB[s] = dn;
  }
}

// ---- gather v3: one 16-LANE GROUP per node (4 nodes/wave, 16/block) ----
// The group's 16 lanes hold the full 256B row -> the segment reduce is pure
// register float4 adds: NO shuffles/butterflies (round-10: ~24 bpermutes +
// guard VALU per node was the drag). Fast path n<=8 (94%/99.8% of nodes):
// all 8 list loads then all 8 row loads issue back-to-back = 32 row-chains
// in flight per wave, 3 memory rounds per node, lockstep across groups.
__global__ void k_gather(const int* __restrict__ offA, const int* __restrict__ degA,
                         const int* __restrict__ listA,
                         const int* __restrict__ offB, const int* __restrict__ degB,
                         const int* __restrict__ listB,
                         const float* __restrict__ emb,
                         float* __restrict__ aggr, float* __restrict__ lse, int gN) {
  int tid = threadIdx.x;
  int l16 = tid & 15, grp = tid >> 4;  // 16 groups per block
  bool taskA = blockIdx.x < gN;
  int node = (taskA ? blockIdx.x : blockIdx.x - gN) * 16 + grp;
  if (node >= NNODE) return;
  if (taskA) {
    int o = offA[node], n = degA[node];
    float4 acc = {0.f, 0.f, 0.f, 0.f};
    if (n <= 8) {
      int e[8];
#pragma unroll
      for (int i = 0; i < 8; ++i) e[i] = (i < n) ? listA[o + i] : -1;
      float4 v[8];
#pragma unroll
      for (int i = 0; i < 8; ++i) {
        v[i] = (float4){0.f, 0.f, 0.f, 0.f};
        if (e[i] >= 0) v[i] = *(const float4*)(emb + (size_t)e[i] * 64 + 4 * l16);
      }
#pragma unroll
      for (int i = 0; i < 8; ++i) {
        acc.x += v[i].x; acc.y += v[i].y; acc.z += v[i].z; acc.w += v[i].w;
      }
    } else {
      float4 a0 = {0.f, 0.f, 0.f, 0.f}, a1 = a0, a2 = a0, a3 = a0;
      for (int i = 0; i < n; i += 4) {
        int e0 = listA[o + i];
        int e1 = (i + 1 < n) ? listA[o + i + 1] : -1;
        int e2 = (i + 2 < n) ? listA[o + i + 2] : -1;
        int e3 = (i + 3 < n) ? listA[o + i + 3] : -1;
        float4 v0 = *(const float4*)(emb + (size_t)e0 * 64 + 4 * l16);
        a0.x += v0.x; a0.y += v0.y; a0.z += v0.z; a0.w += v0.w;
        if (e1 >= 0) {
          float4 v = *(const float4*)(emb + (size_t)e1 * 64 + 4 * l16);
          a1.x += v.x; a1.y += v.y; a1.z += v.z; a1.w += v.w;
        }
        if (e2 >= 0) {
          float4 v = *(const float4*)(emb + (size_t)e2 * 64 + 4 * l16);
          a2.x += v.x; a2.y += v.y; a2.z += v.z; a2.w += v.w;
        }
        if (e3 >= 0) {
          float4 v = *(const float4*)(emb + (size_t)e3 * 64 + 4 * l16);
          a3.x += v.x; a3.y += v.y; a3.z += v.z; a3.w += v.w;
        }
      }
      acc.x = (a0.x + a1.x) + (a2.x + a3.x);
      acc.y = (a0.y + a1.y) + (a2.y + a3.y);
      acc.z = (a0.z + a1.z) + (a2.z + a3.z);
      acc.w = (a0.w + a1.w) + (a2.w + a3.w);
    }
    *(float4*)(aggr + (size_t)node * 64 + 4 * l16) = acc;  // empty -> 0
  } else {
    int o = offB[node], n = degB[node];
    if (n == 0) return;  // lse only read at nodes with c2l out-edges
    float4 res;
    if (n <= 8) {
      float4 v[8];
#pragma unroll
      for (int i = 0; i < 8; ++i) {
        v[i] = (float4){-INFINITY, -INFINITY, -INFINITY, -INFINITY};
        if (i < n) {
          int d = listB[o + i];
          v[i] = *(const float4*)(emb + (size_t)d * 64 + 4 * l16);
        }
      }
      float4 m = v[0];
#pragma unroll
      for (int i = 1; i < 8; ++i) {
        m.x = fmaxf(m.x, v[i].x); m.y = fmaxf(m.y, v[i].y);
        m.z = fmaxf(m.z, v[i].z); m.w = fmaxf(m.w, v[i].w);
      }
      float4 s = {0.f, 0.f, 0.f, 0.f};
#pragma unroll
      for (int i = 0; i < 8; ++i) {  // exp(-inf - m) = 0 for empty slots
        s.x += __expf(v[i].x - m.x); s.y += __expf(v[i].y - m.y);
        s.z += __expf(v[i].z - m.z); s.w += __expf(v[i].w - m.w);
      }
      res.x = __logf(s.x) + m.x; res.y = __logf(s.y) + m.y;
      res.z = __logf(s.z) + m.z; res.w = __logf(s.w) + m.w;
    } else {
      float4 m = {-INFINITY, -INFINITY, -INFINITY, -INFINITY};
      for (int i = 0; i < n; i += 2) {
        int d0 = listB[o + i];
        int d1 = (i + 1 < n) ? listB[o + i + 1] : -1;
        float4 v0 = *(const float4*)(emb + (size_t)d0 * 64 + 4 * l16);
        m.x = fmaxf(m.x, v0.x); m.y = fmaxf(m.y, v0.y);
        m.z = fmaxf(m.z, v0.z); m.w = fmaxf(m.w, v0.w);
        if (d1 >= 0) {
          float4 v = *(const float4*)(emb + (size_t)d1 * 64 + 4 * l16);
          m.x = fmaxf(m.x, v.x); m.y = fmaxf(m.y, v.y);
          m.z = fmaxf(m.z, v.z); m.w = fmaxf(m.w, v.w);
        }
      }
      float4 s = {0.f, 0.f, 0.f, 0.f};
      for (int i = 0; i < n; i += 2) {
        int d0 = listB[o + i];
        int d1 = (i + 1 < n) ? listB[o + i + 1] : -1;
        float4 v0 = *(const float4*)(emb + (size_t)d0 * 64 + 4 * l16);
        s.x += __expf(v0.x - m.x); s.y += __expf(v0.y - m.y);
        s.z += __expf(v0.z - m.z); s.w += __expf(v0.w - m.w);
        if (d1 >= 0) {
          float4 v = *(const float4*)(emb + (size_t)d1 * 64 + 4 * l16);
          s.x += __expf(v.x - m.x); s.y += __expf(v.y - m.y);
          s.z += __expf(v.z - m.z); s.w += __expf(v.w - m.w);
        }
      }
      res.x = __logf(s.x) + m.x; res.y = __logf(s.y) + m.y;
      res.z = __logf(s.z) + m.z; res.w = __logf(s.w) + m.w;
    }
    *(float4*)(lse + (size_t)node * 64 + 4 * l16) = res;  // s >= 1 (max attained)
  }
}

// ======================= weight prep =======================
// Frag-ordered bf16 hi/lo. value = W[32s + 8*(lane>>4) + j][16c + (lane&15)].
// Elem offsets: l2c L1/L2/L3: 0/4096/8192; merge_W0: 12288 (K=128);
// merge_W L1/L2: 20480/24576; c2l L1/L2/L3: 28672/32768/36864. Total 40960.
__global__ void k_prepw(const float* __restrict__ l2cW, const float* __restrict__ mW0,
                        const float* __restrict__ mW, const float* __restrict__ c2lW,
                        unsigned short* __restrict__ WH, unsigned short* __restrict__ WL) {
  int tid = blockIdx.x * 256 + threadIdx.x;
  if (tid >= 40960) return;
  const float* src;
  int base;
  if (tid < 12288) {
    int m = tid / 4096; src = l2cW + m * 4096; base = m * 4096;
  } else if (tid < 20480) {
    src = mW0; base = 12288;
  } else if (tid < 28672) {
    int m = (tid - 20480) / 4096; src = mW + m * 4096; base = 20480 + m * 4096;
  } else {
    int m = (tid - 28672) / 4096; src = c2lW + m * 4096; base = 28672 + m * 4096;
  }
  int local = tid - base;
  int f = local >> 9;           // frag id = s*4+c
  int l = (local >> 3) & 63;    // lane
  int j = local & 7;            // elem
  int s = f >> 2, c = f & 3;
  int k = 32 * s + 8 * (l >> 4) + j;
  int col = 16 * c + (l & 15);
  float v = src[k * 64 + col];
  unsigned short hh = f2bf(v);
  WH[tid] = hh;
  WL[tid] = f2bf(v - bf2f(hh));
}

// ======================= MFMA MLP machinery =======================
// Wave-private LDS tile xs[16 rows][64 cols] f32, XOR-swizzled:
//   dword(row,col) = row*64 + (((col>>2) ^ row) & 15)*4 + (col & 3)
// Weights staged per-layer into block-shared LDS (16 KB hi+lo).

__device__ __forceinline__ void split8(float t0, float t1, float t2, float t3,
                                       float t4, float t5, float t6, float t7,
                                       bf16x8& ah, bf16x8& al) {
  unsigned short h;
  h = f2bf_hw(t0); ah[0] = (short)h; al[0] = (short)f2bf_hw(t0 - bf2f(h));
  h = f2bf_hw(t1); ah[1] = (short)h; al[1] = (short)f2bf_hw(t1 - bf2f(h));
  h = f2bf_hw(t2); ah[2] = (short)h; al[2] = (short)f2bf_hw(t2 - bf2f(h));
  h = f2bf_hw(t3); ah[3] = (short)h; al[3] = (short)f2bf_hw(t3 - bf2f(h));
  h = f2bf_hw(t4); ah[4] = (short)h; al[4] = (short)f2bf_hw(t4 - bf2f(h));
  h = f2bf_hw(t5); ah[5] = (short)h; al[5] = (short)f2bf_hw(t5 - bf2f(h));
  h = f2bf_hw(t6); ah[6] = (short)h; al[6] = (short)f2bf_hw(t6 - bf2f(h));
  h = f2bf_hw(t7); ah[7] = (short)h; al[7] = (short)f2bf_hw(t7 - bf2f(h));
}

// Stage 4096 weight elems (hi+lo, 8 KB each) global->LDS, block-cooperative.
__device__ __forceinline__ void stage_w(const unsigned short* __restrict__ WH,
                                        const unsigned short* __restrict__ WL, int off,
                                        unsigned short* lwh, unsigned short* lwl, int tid) {
  __syncthreads();  // all waves done reading previous layer's weights
  const uint4* gh = (const uint4*)(WH + off);
  const uint4* gl = (const uint4*)(WL + off);
  uint4* sh = (uint4*)lwh;
  uint4* sl = (uint4*)lwl;
#pragma unroll
  for (int t = 0; t < 2; ++t) {
    int i = tid + 256 * t;  // 512 uint4 per array
    sh[i] = gh[i];
    sl[i] = gl[i];
  }
  __syncthreads();
}

__device__ __forceinline__ void acc_init(const float* __restrict__ bias, int col15,
                                         f32x4 (&acc)[4]) {
#pragma unroll
  for (int c = 0; c < 4; ++c) {
    float bv = bias[16 * c + col15];
    acc[c] = (f32x4){bv, bv, bv, bv};
  }
}

__device__ __forceinline__ void acc_relu(f32x4 (&acc)[4]) {
#pragma unroll
  for (int c = 0; c < 4; ++c)
#pragma unroll
    for (int r = 0; r < 4; ++r) acc[c][r] = fmaxf(acc[c][r], 0.f);
}

// Accumulate NS K-slices from LDS weights. FLIPALL: read partner row (t^1).
// Split-bf16: acc += al*wh + ah*wl + ah*wh (misses only lo*lo ~ 2^-18).
template <int NS, bool FLIPALL>
__device__ __forceinline__ void mfma_accum(const float* xw, int lane,
                                           const unsigned short* lwh,
                                           const unsigned short* lwl, f32x4 (&acc)[4]) {
  int col15 = lane & 15, hq = lane >> 4;
  int arow = FLIPALL ? (col15 ^ 1) : col15;
  const float* xr = xw + arow * 64;
#pragma unroll
  for (int s = 0; s < NS; ++s) {
    float4 A0 = *(const float4*)(xr + ((((8 * s + 2 * hq + 0) ^ arow) & 15) << 2));
    float4 A1 = *(const float4*)(xr + ((((8 * s + 2 * hq + 1) ^ arow) & 15) << 2));
    bf16x8 ah, al;
    split8(A0.x, A0.y, A0.z, A0.w, A1.x, A1.y, A1.z, A1.w, ah, al);
#pragma unroll
    for (int c = 0; c < 4; ++c) {
      bf16x8 wh = *(const bf16x8*)(lwh + ((s * 4 + c) * 64 + lane) * 8);
      bf16x8 wl = *(const bf16x8*)(lwl + ((s * 4 + c) * 64 + lane) * 8);
      acc[c] = __builtin_amdgcn_mfma_f32_16x16x32_bf16(al, wh, acc[c], 0, 0, 0);
      acc[c] = __builtin_amdgcn_mfma_f32_16x16x32_bf16(ah, wl, acc[c], 0, 0, 0);
      acc[c] = __builtin_amdgcn_mfma_f32_16x16x32_bf16(ah, wh, acc[c], 0, 0, 0);
    }
  }
}

__device__ __forceinline__ void commitA(float* xw, int lane, const f32x4 (&acc)[4]) {
  int col15 = lane & 15, hq = lane >> 4;
#pragma unroll
  for (int c = 0; c < 4; ++c)
#pragma unroll
    for (int r = 0; r < 4; ++r) {
      int row = 4 * hq + r, col = 16 * c + col15;
      xw[row * 64 + ((((col >> 2) ^ row) & 15) << 2) + (col & 3)] = acc[c][r];
    }
}

// ---- l2c: 3-layer MLP -> pair merge (K=128, staged as 2 halves) -> 2-layer MLP ----
__global__ void __launch_bounds__(256, 4)
k_l2c(const int* __restrict__ ei, const int* __restrict__ l2ci,
      const float* __restrict__ emb, const float* __restrict__ aggr,
      const unsigned short* __restrict__ WH, const unsigned short* __restrict__ WL,
      const float* __restrict__ l2cb, const float* __restrict__ mb0,
      const float* __restrict__ mb, float* __restrict__ out) {
  __shared__ float xs[4][1024];
  __shared__ unsigned short lwh[4096];
  __shared__ unsigned short lwl[4096];
  int tid = threadIdx.x;
  int lane = tid & 63, w = tid >> 6;
  float* xw = xs[w];
  int rbase = (blockIdx.x * 4 + w) * 16;
  int col15 = lane & 15, hq = lane >> 4;
  int rin = min(rbase + col15, HEDGE - 1);
  int j = l2ci[rin];
  int sN = ei[2 * j], dN = ei[2 * j + 1];
  const float* ap = aggr + (size_t)sN * 64 + 16 * hq;
  const float* ep = emb + (size_t)dN * 64 + 16 * hq;
#pragma unroll
  for (int q = 0; q < 4; ++q) {
    float4 a = *(const float4*)(ap + 4 * q);
    float4 e = *(const float4*)(ep + 4 * q);
    float4 v = {a.x - e.x, a.y - e.y, a.z - e.z, a.w - e.w};
    *(float4*)(xw + col15 * 64 + ((((4 * hq + q) ^ col15) & 15) << 2)) = v;
  }
  f32x4 acc[4];
  stage_w(WH, WL, 0, lwh, lwl, tid);
  acc_init(l2cb, col15, acc);       mfma_accum<2, false>(xw, lane, lwh, lwl, acc);
  acc_relu(acc);                    commitA(xw, lane, acc);
  stage_w(WH, WL, 4096, lwh, lwl, tid);
  acc_init(l2cb + 64, col15, acc);  mfma_accum<2, false>(xw, lane, lwh, lwl, acc);
  acc_relu(acc);                    commitA(xw, lane, acc);
  stage_w(WH, WL, 8192, lwh, lwl, tid);
  acc_init(l2cb + 128, col15, acc); mfma_accum<2, false>(xw, lane, lwh, lwl, acc);
  commitA(xw, lane, acc);           // msg
  stage_w(WH, WL, 12288, lwh, lwl, tid);   // merge own-half (K rows 0..63)
  acc_init(mb0, col15, acc);        mfma_accum<2, false>(xw, lane, lwh, lwl, acc);
  stage_w(WH, WL, 16384, lwh, lwl, tid);   // merge flip-half (partner msg)
  mfma_accum<2, true>(xw, lane, lwh, lwl, acc);
  acc_relu(acc);                    commitA(xw, lane, acc);
  stage_w(WH, WL, 20480, lwh, lwl, tid);
  acc_init(mb, col15, acc);         mfma_accum<2, false>(xw, lane, lwh, lwl, acc);
  acc_relu(acc);                    commitA(xw, lane, acc);
  stage_w(WH, WL, 24576, lwh, lwl, tid);
  acc_init(mb + 64, col15, acc);    mfma_accum<2, false>(xw, lane, lwh, lwl, acc);
  int jo[4];
#pragma unroll
  for (int r = 0; r < 4; ++r) {
    int rr = rbase + 4 * hq + r;
    jo[r] = (rr < HEDGE) ? l2ci[rr] : -1;
  }
#pragma unroll
  for (int c = 0; c < 4; ++c)
#pragma unroll
    for (int r = 0; r < 4; ++r)
      if (jo[r] >= 0) out[(size_t)jo[r] * 64 + 16 * c + col15] = acc[c][r];
}

// ---- c2l: 3-layer MLP on (lse[src] - e) ----
__global__ void __launch_bounds__(256, 4)
k_c2l(const int* __restrict__ ei, const int* __restrict__ c2li,
      const float* __restrict__ emb, const float* __restrict__ lse,
      const unsigned short* __restrict__ WH, const unsigned short* __restrict__ WL,
      const float* __restrict__ c2lb, float* __restrict__ out) {
  __shared__ float xs[4][1024];
  __shared__ unsigned short lwh[4096];
  __shared__ unsigned short lwl[4096];
  int tid = threadIdx.x;
  int lane = tid & 63, w = tid >> 6;
  float* xw = xs[w];
  int rbase = (blockIdx.x * 4 + w) * 16;
  int col15 = lane & 15, hq = lane >> 4;
  int rin = min(rbase + col15, HEDGE - 1);
  int j = c2li[rin];
  int sN = ei[2 * j], dN = ei[2 * j + 1];
  const float* ap = lse + (size_t)sN * 64 + 16 * hq;
  const float* ep = emb + (size_t)dN * 64 + 16 * hq;
#pragma unroll
  for (int q = 0; q < 4; ++q) {
    float4 a = *(const float4*)(ap + 4 * q);
    float4 e = *(const float4*)(ep + 4 * q);
    float4 v = {a.x - e.x, a.y - e.y, a.z - e.z, a.w - e.w};
    *(float4*)(xw + col15 * 64 + ((((4 * hq + q) ^ col15) & 15) << 2)) = v;
  }
  f32x4 acc[4];
  stage_w(WH, WL, 28672, lwh, lwl, tid);
  acc_init(c2lb, col15, acc);       mfma_accum<2, false>(xw, lane, lwh, lwl, acc);
  acc_relu(acc);                    commitA(xw, lane, acc);
  stage_w(WH, WL, 32768, lwh, lwl, tid);
  acc_init(c2lb + 64, col15, acc);  mfma_accum<2, false>(xw, lane, lwh, lwl, acc);
  acc_relu(acc);                    commitA(xw, lane, acc);
  stage_w(WH, WL, 36864, lwh, lwl, tid);
  acc_init(c2lb + 128, col15, acc); mfma_accum<2, false>(xw, lane, lwh, lwl, acc);
  int jo[4];
#pragma unroll
  for (int r = 0; r < 4; ++r) {
    int rr = rbase + 4 * hq + r;
    jo[r] = (rr < HEDGE) ? c2li[rr] : -1;
  }
#pragma unroll
  for (int c = 0; c < 4; ++c)
#pragma unroll
    for (int r = 0; r < 4; ++r)
      if (jo[r] >= 0) out[(size_t)jo[r] * 64 + 16 * c + col15] = acc[c][r];
}

extern "C" void kernel_launch(void* const* d_in, const int* in_sizes, int n_in,
                              void* d_out, int out_size, void* d_ws, size_t ws_size,
                              hipStream_t stream) {
  const int* ei = (const int*)d_in[0];
  const int* l2ci = (const int*)d_in[1];
  const int* c2li = (const int*)d_in[2];
  const float* emb = (const float*)d_in[3];
  const float* l2cW = (const float*)d_in[4];
  const float* l2cb = (const float*)d_in[5];
  const float* c2lW = (const float*)d_in[6];
  const float* c2lb = (const float*)d_in[7];
  const float* mW0 = (const float*)d_in[8];
  const float* mb0 = (const float*)d_in[9];
  const float* mW = (const float*)d_in[10];
  const float* mb = (const float*)d_in[11];
  float* out = (float*)d_out;

  char* ws = (char*)d_ws;
  const size_t NB = (size_t)NNODE * 64 * 4;  // 51.2 MB per node-buffer
  float* aggr = (float*)ws;
  float* lse = (float*)(ws + NB);
  unsigned short* WH = (unsigned short*)(ws + 2 * NB);
  unsigned short* WL = WH + 40960;  // 163840 B total for weights
  char* p = ws + 2 * NB + 163840;
  int* degA = (int*)p; p += NNODE * 4;
  int* degB = (int*)p; p += NNODE * 4;
  int* cursors = (int*)p; p += 2 * 4;
  int* offA = (int*)p; p += NNODE * 4;
  int* offB = (int*)p; p += NNODE * 4;
  int* curA = (int*)p; p += NNODE * 4;
  int* curB = (int*)p; p += NNODE * 4;
  int* listA = (int*)p; p += (size_t)NEDGE * 4;
  int* listB = (int*)p; p += (size_t)HEDGE * 4;

  hipMemsetAsync(degA, 0, (2 * (size_t)NNODE + 2) * 4, stream);  // degA,degB,cursors

  dim3 B(256);
  int gE = (NEDGE + 255) / 256;
  k_deg<<<gE, B, 0, stream>>>(ei, c2li, degA, degB);
  k_alloc<<<(NNODE + 255) / 256, B, 0, stream>>>(degA, offA, curA, degB, offB, curB, cursors);
  k_fill<<<gE, B, 0, stream>>>(ei, c2li, curA, listA, curB, listB);
  k_prepw<<<160, B, 0, stream>>>(l2cW, mW0, mW, c2lW, WH, WL);
  int gN = (NNODE + 15) / 16;  // 16 nodes per block (one per 16-lane group)
  k_gather<<<2 * gN, B, 0, stream>>>(offA, degA, listA, offB, degB, listB, emb, aggr, lse, gN);
  int gmlp = (HEDGE / 16 + 3) / 4;
  k_l2c<<<gmlp, B, 0, stream>>>(ei, l2ci, emb, aggr, WH, WL, l2cb, mb0, mb, out);
  k_c2l<<<gmlp, B, 0, stream>>>(ei, c2li, emb, lse, WH, WL, c2lb, out);
}